// Round 4
// baseline (46.371 us; speedup 1.0000x reference)
//
#include <hip/hip_runtime.h>

// Sliding-window min (window=64) over rows of T=8192 fp32.
// Gil-Werman, 4 elems/lane, segment = 64 elems = one 16-lane DPP row.
//
// R4 changes vs R3:
//  - Each 16-lane group owns a contiguous 512-elem sub-range (8 segments)
//    with its own 64-elem halo prologue -> the segment-to-segment carry is
//    IN-LANE (no cross-group rotate, no shuffle on the dependency chain).
//  - All scans are within 16-lane rows -> pure DPP (row_shr/row_shl) +
//    v_min on the VALU pipe. ZERO ds_bpermute / LDS ops in the kernel.
//    bound_ctrl=0 with old=INIT_VAL gives the 9999-padding semantics free.
//  - Explicit prefetch depth 4 (affine addresses) for memory-level
//    parallelism: ~4 x 256B x 32 waves = 32KB in flight per CU.

constexpr int T = 8192;
constexpr float INIT_VAL = 9999.0f;
constexpr int WAVE = 64;
constexpr int WAVES_PER_BLOCK = 4;
constexpr int GRP_ELEMS = 512;                       // per 16-lane group
constexpr int ITERS = GRP_ELEMS / 64;                // 8 segments per group

typedef float f4v __attribute__((ext_vector_type(4)));

// DPP move: dst = (row-relative shift of src); invalid lanes get `old`.
// row_shr:N = 0x110|N (lane i reads lane i-N, like __shfl_up within 16)
// row_shl:N = 0x100|N (lane i reads lane i+N, like __shfl_down within 16)
template <int CTRL>
__device__ __forceinline__ float dppmov(float old, float src) {
    return __builtin_bit_cast(
        float, __builtin_amdgcn_update_dpp(
                   __builtin_bit_cast(int, old), __builtin_bit_cast(int, src),
                   CTRL, 0xF, 0xF, false));
}

__global__ __launch_bounds__(WAVE * WAVES_PER_BLOCK)
void tlalw_kernel(const float* __restrict__ x, float* __restrict__ y) {
    const int lane = threadIdx.x & 63;
    const int g = lane & 15;                  // position within DPP row
    const int grp = lane >> 4;                // group 0..3 within wave
    const int wv = threadIdx.x >> 6;
    const long long rowBase = (long long)blockIdx.x * T;
    const float* __restrict__ xr = x + rowBase;
    float* __restrict__ yr = y + rowBase;

    // this group's contiguous sub-range within the row
    const int gbase = wv * (WAVES_PER_BLOCK * GRP_ELEMS) / WAVES_PER_BLOCK * WAVES_PER_BLOCK
                      * 0 /* see below */ + (wv * 4 + grp) * GRP_ELEMS;

    // carry_j : Sshift_j of the preceding segment, in-lane.
    float carry0, carry1, carry2, carry3;

    // Prologue: halo segment [gbase-64, gbase); 9999-pad at row start.
    {
        f4v v;
        if (gbase > 0) v = *(const f4v*)(xr + gbase - 64 + 4 * g);
        else v = (f4v){INIT_VAL, INIT_VAL, INIT_VAL, INIT_VAL};
        float s3 = v.w, s2 = fminf(v.z, s3), s1 = fminf(v.y, s2), s0 = fminf(v.x, s1);
        float eS = dppmov<0x101>(INIT_VAL, s0);
        eS = fminf(eS, dppmov<0x101>(INIT_VAL, eS));
        eS = fminf(eS, dppmov<0x102>(INIT_VAL, eS));
        eS = fminf(eS, dppmov<0x104>(INIT_VAL, eS));
        eS = fminf(eS, dppmov<0x108>(INIT_VAL, eS));
        float S0 = fminf(eS, s0);
        carry0 = fminf(eS, s1);
        carry1 = fminf(eS, s2);
        carry2 = fminf(eS, s3);
        carry3 = dppmov<0x101>(INIT_VAL, S0);
    }

    // Prefetched main loop, fully unrolled (static indices -> registers).
    f4v vb[ITERS];
    #pragma unroll
    for (int i = 0; i < 4; ++i)
        vb[i] = *(const f4v*)(xr + gbase + i * 64 + 4 * g);

    #pragma unroll
    for (int it = 0; it < ITERS; ++it) {
        if (it + 4 < ITERS)
            vb[it + 4] = *(const f4v*)(xr + gbase + (it + 4) * 64 + 4 * g);

        const f4v v = vb[it];
        float p0 = v.x, p1 = fminf(p0, v.y), p2 = fminf(p1, v.z), p3 = fminf(p2, v.w);
        float s3 = v.w, s2 = fminf(v.z, s3), s1 = fminf(v.y, s2), s0 = fminf(v.x, s1);

        // exclusive prefix-min of lane aggregate (p3) within the 16-lane row
        float eP = dppmov<0x111>(INIT_VAL, p3);
        eP = fminf(eP, dppmov<0x111>(INIT_VAL, eP));
        eP = fminf(eP, dppmov<0x112>(INIT_VAL, eP));
        eP = fminf(eP, dppmov<0x114>(INIT_VAL, eP));
        eP = fminf(eP, dppmov<0x118>(INIT_VAL, eP));

        // exclusive suffix-min of lane aggregate (s0) within the row
        float eS = dppmov<0x101>(INIT_VAL, s0);
        eS = fminf(eS, dppmov<0x101>(INIT_VAL, eS));
        eS = fminf(eS, dppmov<0x102>(INIT_VAL, eS));
        eS = fminf(eS, dppmov<0x104>(INIT_VAL, eS));
        eS = fminf(eS, dppmov<0x108>(INIT_VAL, eS));

        // segment prefix mins and output
        f4v o;
        o.x = fminf(fminf(eP, p0), carry0);
        o.y = fminf(fminf(eP, p1), carry1);
        o.z = fminf(fminf(eP, p2), carry2);
        o.w = fminf(fminf(eP, p3), carry3);
        __builtin_nontemporal_store(o, (f4v*)(yr + gbase + it * 64 + 4 * g));

        // next carry: suffix mins shifted by one element
        float S0 = fminf(eS, s0);
        carry0 = fminf(eS, s1);
        carry1 = fminf(eS, s2);
        carry2 = fminf(eS, s3);
        carry3 = dppmov<0x101>(INIT_VAL, S0);
    }
}

extern "C" void kernel_launch(void* const* d_in, const int* in_sizes, int n_in,
                              void* d_out, int out_size, void* d_ws, size_t ws_size,
                              hipStream_t stream) {
    const float* x = (const float*)d_in[0];
    float* y = (float*)d_out;
    const int B = in_sizes[0] / T; // 4096 rows
    tlalw_kernel<<<B, WAVE * WAVES_PER_BLOCK, 0, stream>>>(x, y);
}